// Round 15
// baseline (294.107 us; speedup 1.0000x reference)
//
#include <hip/hip_runtime.h>
#include <math.h>

#define I_DIM 1025
#define J_DIM 1024
#define K_DIM 8
#define N_ITER 10
#define EPS 1e-20f
#define REG 1e-6f
#define MODE_CD  1
#define MODE_NMF 2

__device__ __forceinline__ float __frcp(float x){ return __builtin_amdgcn_rcpf(x); }

__device__ __forceinline__ float2 cmul(float2 a, float2 b){
  return make_float2(a.x*b.x - a.y*b.y, a.x*b.y + a.y*b.x);
}
__device__ __forceinline__ float2 cadd(float2 a, float2 b){
  return make_float2(a.x+b.x, a.y+b.y);
}
__device__ __forceinline__ float2 csub(float2 a, float2 b){
  return make_float2(a.x-b.x, a.y-b.y);
}
__device__ __forceinline__ float2 cconj(float2 a){ return make_float2(a.x, -a.y); }
__device__ __forceinline__ float2 cscale(float2 a, float s){ return make_float2(a.x*s, a.y*s); }
__device__ __forceinline__ float2 cdivc(float2 a, float2 d){
  float inv = 1.0f/(d.x*d.x + d.y*d.y);
  return make_float2((a.x*d.x + a.y*d.y)*inv, (a.y*d.x - a.x*d.y)*inv);
}

// ---- setup: init Tpair/V/W + transpose X -> Xc4 [i][j], XcT [j][i] ----
// Tpair [n][k][i] float2 = (t_used, t_current); V [n][j][k] (float4-pair)
__global__ __launch_bounds__(256) void k_setup(
    const float2* __restrict__ X, const float* __restrict__ T0, const float* __restrict__ V0,
    float4* __restrict__ Xc4, float4* __restrict__ XcT,
    float2* __restrict__ Tp, float* __restrict__ Vw, float2* __restrict__ Wm){
  __shared__ float4 tile[32][33];
  int b = blockIdx.x, tid = threadIdx.x;
  int gtid = b*256 + tid;
  if (gtid < 2*K_DIM*I_DIM){
    int i = gtid % I_DIM; int rest = gtid / I_DIM;
    int k = rest & 7, n = rest >> 3;
    float t0 = T0[(i*K_DIM+k)*2 + n];            // T0 [I,K,M]
    Tp[gtid] = make_float2(t0, t0);
  }
  if (gtid < 2*K_DIM*J_DIM){
    int n = gtid >> 13;
    int j = (gtid >> 3) & (J_DIM-1);
    int k = gtid & 7;
    Vw[gtid] = V0[(k*J_DIM+j)*2 + n];            // V0 [K,J,M] -> [n][j][k]
  }
  if (gtid < I_DIM*4){
    int rc = gtid & 3;
    Wm[gtid] = make_float2((rc==0||rc==3)?1.0f:0.0f, 0.0f);
  }
  int ib = b / 32, jb = b % 32;
  int i0 = ib*32, j0 = jb*32;
  int tx = tid & 31, ty = tid >> 5;   // ty 0..7
  #pragma unroll
  for (int r=0;r<4;r++){
    int jl = ty + r*8; int i = i0 + tx;
    if (i < I_DIM){
      float2 a = X[(size_t)(0*J_DIM + j0 + jl)*I_DIM + i];
      float2 c = X[(size_t)(1*J_DIM + j0 + jl)*I_DIM + i];
      float4 val = make_float4(a.x, a.y, c.x, c.y);
      tile[jl][tx] = val;
      XcT[(size_t)(j0+jl)*I_DIM + i] = val;      // coalesced in i
    }
  }
  __syncthreads();
  #pragma unroll
  for (int r=0;r<4;r++){
    int il = ty + r*8; int i = i0 + il;
    if (i < I_DIM) Xc4[(size_t)i*J_DIM + j0 + tx] = tile[tx][il];
  }
}

// ---- fused: [CD + 2x2 solve -> W_i] then [NMF T-update for next body] ----
// V in [n][j][k] float4 pairs; T in Tpair float2 (write old+new in one store).
template<int MODE>
__global__ __launch_bounds__(256) void k_cda(const float4* __restrict__ Xc4,
      float2* __restrict__ Tp, const float4* __restrict__ Vw4,
      float2* __restrict__ Wm){
  int i = blockIdx.x, tid = threadIdx.x;
  int n = tid >> 7, jl = tid & 127;     // waves 0,1 -> n=0; waves 2,3 -> n=1
  __shared__ float redD[4][4];
  __shared__ float redT[4][16];
  __shared__ float wsh[8];

  float t[8];
  #pragma unroll
  for (int k=0;k<8;k++) t[k] = Tp[(size_t)(n*K_DIM+k)*I_DIM + i].y;

  const float4* vb = Vw4 + (size_t)n*J_DIM*2;
  float r_s[8], q_s[8];
  #pragma unroll
  for (int s=0;s<8;s++){
    int j = jl + 128*s;
    float4 va = vb[j*2+0], vc = vb[j*2+1];
    r_s[s] = t[0]*va.x + t[1]*va.y + t[2]*va.z + t[3]*va.w
           + t[4]*vc.x + t[5]*vc.y + t[6]*vc.z + t[7]*vc.w;
    q_s[s] = __frcp(r_s[s] + EPS);
  }

  const float4* xb = Xc4 + (size_t)i*J_DIM + jl;
  float4 x_s[8];
  #pragma unroll
  for (int s=0;s<8;s++) x_s[s] = xb[128*s];     // coalesced

  if (MODE & MODE_CD){
    float d00=0.0f, d11=0.0f, dre=0.0f, dim_=0.0f;
    #pragma unroll
    for (int s=0;s<8;s++){
      float4 x = x_s[s]; float q = q_s[s];
      d00 += (x.x*x.x + x.y*x.y)*q;
      d11 += (x.z*x.z + x.w*x.w)*q;
      dre += (x.x*x.z + x.y*x.w)*q;   // Re(x0*conj(x1))
      dim_ += (x.y*x.z - x.x*x.w)*q;  // Im(x0*conj(x1))
    }
    #pragma unroll
    for (int off=32; off>0; off>>=1){
      d00 += __shfl_down(d00,off); d11 += __shfl_down(d11,off);
      dre += __shfl_down(dre,off); dim_ += __shfl_down(dim_,off);
    }
    {
      int lane = tid&63, wv = tid>>6;
      if (lane==0){ redD[wv][0]=d00; redD[wv][1]=d11; redD[wv][2]=dre; redD[wv][3]=dim_; }
    }
    __syncthreads();
    if (tid==0){
      const float invJ = 1.0f/(float)J_DIM;
      float D[2][4];
      #pragma unroll
      for (int c=0;c<4;c++){
        D[0][c] = (redD[0][c]+redD[1][c])*invJ;
        D[1][c] = (redD[2][c]+redD[3][c])*invJ;
      }
      float2 w00 = Wm[i*4+0], w01 = Wm[i*4+1], w10 = Wm[i*4+2], w11 = Wm[i*4+3];
      #pragma unroll
      for (int nn=0;nn<2;nn++){
        float d00_ = D[nn][0] + REG, d11_ = D[nn][1] + REG;
        float2 d01 = make_float2(D[nn][2], D[nn][3]);
        float2 d10 = cconj(d01);
        float2 A00 = cadd(cscale(w00, d00_), cmul(w01, d10));
        float2 A01 = cadd(cmul(w00, d01), cscale(w01, d11_));
        float2 A10 = cadd(cscale(w10, d00_), cmul(w11, d10));
        float2 A11 = cadd(cmul(w10, d01), cscale(w11, d11_));
        float2 det = csub(cmul(A00,A11), cmul(A01,A10));
        float2 bu0, bu1;
        if (nn==0){ bu0 = A11; bu1 = make_float2(-A10.x, -A10.y); }
        else      { bu0 = make_float2(-A01.x, -A01.y); bu1 = A00; }
        float2 b0 = cdivc(bu0, det);
        float2 b1 = cdivc(bu1, det);
        float quad = d00_*(b0.x*b0.x + b0.y*b0.y) + d11_*(b1.x*b1.x + b1.y*b1.y);
        float2 u = cmul(d01, b1);
        quad += 2.0f*(b0.x*u.x + b0.y*u.y);
        float inv = 1.0f/sqrtf(quad + EPS);
        float2 wn0 = make_float2(b0.x*inv, -b0.y*inv);
        float2 wn1 = make_float2(b1.x*inv, -b1.y*inv);
        if (nn==0){ w00=wn0; w01=wn1; } else { w10=wn0; w11=wn1; }
      }
      Wm[i*4+0]=w00; Wm[i*4+1]=w01; Wm[i*4+2]=w10; Wm[i*4+3]=w11;
      wsh[0]=w00.x; wsh[1]=w00.y; wsh[2]=w01.x; wsh[3]=w01.y;
      wsh[4]=w10.x; wsh[5]=w10.y; wsh[6]=w11.x; wsh[7]=w11.y;
    }
  } else {
    if (tid < 4){ float2 w = Wm[i*4+tid]; wsh[tid*2]=w.x; wsh[tid*2+1]=w.y; }
  }
  __syncthreads();
  if (!(MODE & MODE_NMF)) return;

  float2 w0 = make_float2(wsh[n*4+0], wsh[n*4+1]);
  float2 w1 = make_float2(wsh[n*4+2], wsh[n*4+3]);
  float aN[8] = {0,0,0,0,0,0,0,0};
  float aD[8] = {0,0,0,0,0,0,0,0};
  #pragma unroll
  for (int s=0;s<8;s++){
    float4 x = x_s[s];
    float yre = w0.x*x.x - w0.y*x.y + w1.x*x.z - w1.y*x.w;
    float yim = w0.x*x.y + w0.y*x.x + w1.x*x.w + w1.y*x.z;
    float q = q_s[s];
    float p = (yre*yre + yim*yim)*q*q;
    int j = jl + 128*s;
    float4 va = vb[j*2+0], vc = vb[j*2+1];
    aN[0]+=p*va.x; aN[1]+=p*va.y; aN[2]+=p*va.z; aN[3]+=p*va.w;
    aN[4]+=p*vc.x; aN[5]+=p*vc.y; aN[6]+=p*vc.z; aN[7]+=p*vc.w;
    aD[0]+=q*va.x; aD[1]+=q*va.y; aD[2]+=q*va.z; aD[3]+=q*va.w;
    aD[4]+=q*vc.x; aD[5]+=q*vc.y; aD[6]+=q*vc.z; aD[7]+=q*vc.w;
  }
  #pragma unroll
  for (int k=0;k<8;k++){
    #pragma unroll
    for (int off=32; off>0; off>>=1){
      aN[k] += __shfl_down(aN[k],off);
      aD[k] += __shfl_down(aD[k],off);
    }
  }
  {
    int lane = tid&63, wv = tid>>6;
    if (lane==0){
      #pragma unroll
      for (int k=0;k<8;k++){ redT[wv][k]=aN[k]; redT[wv][k+8]=aD[k]; }
    }
  }
  __syncthreads();
  if ((tid & 127) < 8){
    int kk = tid & 7;
    int wb = (tid>>7)*2;
    float ns = redT[wb][kk]   + redT[wb+1][kk];
    float ds = redT[wb][kk+8] + redT[wb+1][kk+8];
    float tn = t[kk]*sqrtf(ns*__frcp(ds + EPS));
    Tp[(size_t)(n*K_DIM+kk)*I_DIM + i] = make_float2(t[kk], tn);  // (old, new)
  }
}

// ---- V-update: recompute p,q from (XcT, Tpair, W), reduce over I, scale V ----
// grid (J/2, 2); block 256 = 128 i-lanes x 2 j. Tpair: 8 float2 loads per i.
__global__ __launch_bounds__(256) void k_vupd(const float4* __restrict__ XcT,
      const float2* __restrict__ Tp, float* __restrict__ Vw,
      const float2* __restrict__ Wm){
  int n = blockIdx.y;
  int tid = threadIdx.x;
  int jj = tid & 1, ii = tid >> 1;
  int j = blockIdx.x*2 + jj;
  const float4* vj = (const float4*)(Vw + ((size_t)n*J_DIM + j)*8);
  float4 va = vj[0], vc = vj[1];     // broadcast within jj-group
  float aN[8] = {0,0,0,0,0,0,0,0};
  float aD[8] = {0,0,0,0,0,0,0,0};
  const float2* tb = Tp + (size_t)n*K_DIM*I_DIM;
  const float4* xcb = XcT + (size_t)j*I_DIM;
  #pragma unroll 2
  for (int i=ii; i<I_DIM; i+=128){
    float2 tp[8];
    #pragma unroll
    for (int k=0;k<8;k++) tp[k] = tb[(size_t)k*I_DIM + i];   // coalesced float2
    float4 wv = *(const float4*)&Wm[i*4 + n*2];
    float4 x  = xcb[i];                        // coalesced in i
    float r = tp[0].x*va.x+tp[1].x*va.y+tp[2].x*va.z+tp[3].x*va.w
            + tp[4].x*vc.x+tp[5].x*vc.y+tp[6].x*vc.z+tp[7].x*vc.w;
    float yre = wv.x*x.x - wv.y*x.y + wv.z*x.z - wv.w*x.w;
    float yim = wv.x*x.y + wv.y*x.x + wv.z*x.w + wv.w*x.z;
    float q = __frcp(r + EPS);
    float p = (yre*yre + yim*yim)*q*q;
    #pragma unroll
    for (int k=0;k<8;k++){ aN[k] += tp[k].y*p; aD[k] += tp[k].y*q; }
  }
  // reduce over ii within wave (lanes with same jj: even strides down to 2)
  #pragma unroll
  for (int k=0;k<8;k++){
    #pragma unroll
    for (int off=32; off>=2; off>>=1){
      aN[k] += __shfl_down(aN[k],off);
      aD[k] += __shfl_down(aD[k],off);
    }
  }
  __shared__ float red[4][2][16];   // [wave][jj][k | k+8]
  int wv_ = tid>>6, lane = tid&63;
  if (lane < 2){
    #pragma unroll
    for (int k=0;k<8;k++){ red[wv_][lane][k]=aN[k]; red[wv_][lane][k+8]=aD[k]; }
  }
  __syncthreads();
  if (tid < 16){
    int jj2 = tid>>3, k = tid&7;
    float num = red[0][jj2][k]+red[1][jj2][k]+red[2][jj2][k]+red[3][jj2][k];
    float den = red[0][jj2][k+8]+red[1][jj2][k+8]+red[2][jj2][k+8]+red[3][jj2][k+8];
    size_t vi = ((size_t)n*J_DIM + blockIdx.x*2 + jj2)*8 + k;
    Vw[vi] *= sqrtf(num*__frcp(den + EPS));
  }
}

// ---- final: Y = W @ X, write out [N,J,I,2] (transpose via LDS tile) ----
__global__ void k_final(const float4* __restrict__ Xc4, const float2* __restrict__ Wm,
                        float2* __restrict__ out){
  __shared__ float2 yt[2][32][33];
  int i0 = blockIdx.x*32, j0 = blockIdx.y*32;
  int tx = threadIdx.x, ty = threadIdx.y;
  int j = j0 + tx;
  #pragma unroll
  for (int r=0;r<4;r++){
    int il = ty + r*8; int i = i0 + il;
    if (i < I_DIM){
      float4 x = Xc4[(size_t)i*J_DIM + j];
      #pragma unroll
      for (int n=0;n<2;n++){
        float2 a = Wm[i*4+n*2+0], b = Wm[i*4+n*2+1];
        float2 y;
        y.x = a.x*x.x - a.y*x.y + b.x*x.z - b.y*x.w;
        y.y = a.x*x.y + a.y*x.x + b.x*x.w + b.y*x.z;
        yt[n][tx][il] = y;
      }
    }
  }
  __syncthreads();
  int i = i0 + tx;
  if (i < I_DIM){
    #pragma unroll
    for (int n=0;n<2;n++){
      #pragma unroll
      for (int r=0;r<4;r++){
        int jl = ty + r*8;
        out[(size_t)(n*J_DIM + j0 + jl)*I_DIM + i] = yt[n][jl][tx];
      }
    }
  }
}

extern "C" void kernel_launch(void* const* d_in, const int* in_sizes, int n_in,
                              void* d_out, int out_size, void* d_ws, size_t ws_size,
                              hipStream_t stream){
  const float2* X  = (const float2*)d_in[0];   // [M,J,I,2]
  const float*  T0 = (const float*)d_in[1];    // [I,K,M]
  const float*  V0 = (const float*)d_in[2];    // [K,J,M]

  char* ws = (char*)d_ws;
  size_t off = 0;
  auto alloc = [&](size_t bytes)->char*{
    char* p = ws + off; off += (bytes + 255) & ~(size_t)255; return p;
  };
  float4* Xc4  = (float4*)alloc((size_t)I_DIM*J_DIM*sizeof(float4));
  float4* XcT  = (float4*)alloc((size_t)J_DIM*I_DIM*sizeof(float4));
  float2* Tp   = (float2*)alloc((size_t)2*K_DIM*I_DIM*sizeof(float2));
  float*  Vw   = (float*) alloc((size_t)2*J_DIM*K_DIM*sizeof(float));
  float2* Wm   = (float2*)alloc((size_t)I_DIM*4*sizeof(float2));

  k_setup<<<33*32, 256, 0, stream>>>(X, T0, V0, Xc4, XcT, Tp, Vw, Wm);
  // A0: NMF T-update of body 0 (W = identity)
  k_cda<MODE_NMF><<<I_DIM, 256, 0, stream>>>(Xc4, Tp, (const float4*)Vw, Wm);
  for (int it=0; it<N_ITER; it++){
    k_vupd<<<dim3(J_DIM/2, 2), 256, 0, stream>>>(XcT, Tp, Vw, Wm);
    if (it < N_ITER-1)
      k_cda<MODE_CD|MODE_NMF><<<I_DIM, 256, 0, stream>>>(Xc4, Tp, (const float4*)Vw, Wm);
    else
      k_cda<MODE_CD><<<I_DIM, 256, 0, stream>>>(Xc4, Tp, (const float4*)Vw, Wm);
  }
  k_final<<<dim3(33,32), dim3(32,8), 0, stream>>>(Xc4, Wm, (float2*)d_out);
}

// Round 16
// 272.180 us; speedup vs baseline: 1.0806x; 1.0806x over previous
//
#include <hip/hip_runtime.h>
#include <math.h>

#define I_DIM 1025
#define J_DIM 1024
#define K_DIM 8
#define N_ITER 10
#define EPS 1e-20f
#define REG 1e-6f
#define MODE_CD  1
#define MODE_NMF 2

__device__ __forceinline__ float __frcp(float x){ return __builtin_amdgcn_rcpf(x); }

__device__ __forceinline__ float2 cmul(float2 a, float2 b){
  return make_float2(a.x*b.x - a.y*b.y, a.x*b.y + a.y*b.x);
}
__device__ __forceinline__ float2 cadd(float2 a, float2 b){
  return make_float2(a.x+b.x, a.y+b.y);
}
__device__ __forceinline__ float2 csub(float2 a, float2 b){
  return make_float2(a.x-b.x, a.y-b.y);
}
__device__ __forceinline__ float2 cconj(float2 a){ return make_float2(a.x, -a.y); }
__device__ __forceinline__ float2 cscale(float2 a, float s){ return make_float2(a.x*s, a.y*s); }
__device__ __forceinline__ float2 cdivc(float2 a, float2 d){
  float inv = 1.0f/(d.x*d.x + d.y*d.y);
  return make_float2((a.x*d.x + a.y*d.y)*inv, (a.y*d.x - a.x*d.y)*inv);
}

// ---- setup: init T/V/W + transpose X -> Xc4 [i][j], XcT [j][i] ----
// T [n][k][i]; V [n][j][k] (8 floats per j, float4-pair loadable)
__global__ __launch_bounds__(256) void k_setup(
    const float2* __restrict__ X, const float* __restrict__ T0, const float* __restrict__ V0,
    float4* __restrict__ Xc4, float4* __restrict__ XcT,
    float* __restrict__ Tw, float* __restrict__ Vw, float2* __restrict__ Wm){
  __shared__ float4 tile[32][33];
  int b = blockIdx.x, tid = threadIdx.x;
  int gtid = b*256 + tid;
  if (gtid < 2*K_DIM*I_DIM){
    int i = gtid % I_DIM; int rest = gtid / I_DIM;
    int k = rest & 7, n = rest >> 3;
    Tw[gtid] = T0[(i*K_DIM+k)*2 + n];            // T0 [I,K,M] -> [n][k][i]
  }
  if (gtid < 2*K_DIM*J_DIM){
    int n = gtid >> 13;
    int j = (gtid >> 3) & (J_DIM-1);
    int k = gtid & 7;
    Vw[gtid] = V0[(k*J_DIM+j)*2 + n];            // V0 [K,J,M] -> [n][j][k]
  }
  if (gtid < I_DIM*4){
    int rc = gtid & 3;
    Wm[gtid] = make_float2((rc==0||rc==3)?1.0f:0.0f, 0.0f);
  }
  int ib = b / 32, jb = b % 32;
  int i0 = ib*32, j0 = jb*32;
  int tx = tid & 31, ty = tid >> 5;   // ty 0..7
  #pragma unroll
  for (int r=0;r<4;r++){
    int jl = ty + r*8; int i = i0 + tx;
    if (i < I_DIM){
      float2 a = X[(size_t)(0*J_DIM + j0 + jl)*I_DIM + i];
      float2 c = X[(size_t)(1*J_DIM + j0 + jl)*I_DIM + i];
      float4 val = make_float4(a.x, a.y, c.x, c.y);
      tile[jl][tx] = val;
      XcT[(size_t)(j0+jl)*I_DIM + i] = val;      // coalesced in i
    }
  }
  __syncthreads();
  #pragma unroll
  for (int r=0;r<4;r++){
    int il = ty + r*8; int i = i0 + il;
    if (i < I_DIM) Xc4[(size_t)i*J_DIM + j0 + tx] = tile[tx][il];
  }
}

// ---- fused: [CD + 2x2 solve -> W_i] then [NMF T-update for next body] ----
// V in [n][j][k]: 2 float4 loads per (s) step instead of 8 scalar loads.
template<int MODE>
__global__ __launch_bounds__(256) void k_cda(const float4* __restrict__ Xc4,
      float* __restrict__ Tw, float* __restrict__ Told, const float4* __restrict__ Vw4,
      float2* __restrict__ Wm){
  int i = blockIdx.x, tid = threadIdx.x;
  int n = tid >> 7, jl = tid & 127;     // waves 0,1 -> n=0; waves 2,3 -> n=1
  __shared__ float redD[4][4];
  __shared__ float redT[4][16];
  __shared__ float wsh[8];

  float t[8];
  #pragma unroll
  for (int k=0;k<8;k++) t[k] = Tw[(size_t)(n*K_DIM+k)*I_DIM + i];

  const float4* vb = Vw4 + (size_t)n*J_DIM*2;
  float r_s[8], q_s[8];
  #pragma unroll
  for (int s=0;s<8;s++){
    int j = jl + 128*s;
    float4 va = vb[j*2+0], vc = vb[j*2+1];
    r_s[s] = t[0]*va.x + t[1]*va.y + t[2]*va.z + t[3]*va.w
           + t[4]*vc.x + t[5]*vc.y + t[6]*vc.z + t[7]*vc.w;
    q_s[s] = __frcp(r_s[s] + EPS);
  }

  const float4* xb = Xc4 + (size_t)i*J_DIM + jl;
  float4 x_s[8];
  #pragma unroll
  for (int s=0;s<8;s++) x_s[s] = xb[128*s];     // coalesced

  if (MODE & MODE_CD){
    float d00=0.0f, d11=0.0f, dre=0.0f, dim_=0.0f;
    #pragma unroll
    for (int s=0;s<8;s++){
      float4 x = x_s[s]; float q = q_s[s];
      d00 += (x.x*x.x + x.y*x.y)*q;
      d11 += (x.z*x.z + x.w*x.w)*q;
      dre += (x.x*x.z + x.y*x.w)*q;   // Re(x0*conj(x1))
      dim_ += (x.y*x.z - x.x*x.w)*q;  // Im(x0*conj(x1))
    }
    #pragma unroll
    for (int off=32; off>0; off>>=1){
      d00 += __shfl_down(d00,off); d11 += __shfl_down(d11,off);
      dre += __shfl_down(dre,off); dim_ += __shfl_down(dim_,off);
    }
    {
      int lane = tid&63, wv = tid>>6;
      if (lane==0){ redD[wv][0]=d00; redD[wv][1]=d11; redD[wv][2]=dre; redD[wv][3]=dim_; }
    }
    __syncthreads();
    if (tid==0){
      const float invJ = 1.0f/(float)J_DIM;
      float D[2][4];
      #pragma unroll
      for (int c=0;c<4;c++){
        D[0][c] = (redD[0][c]+redD[1][c])*invJ;
        D[1][c] = (redD[2][c]+redD[3][c])*invJ;
      }
      float2 w00 = Wm[i*4+0], w01 = Wm[i*4+1], w10 = Wm[i*4+2], w11 = Wm[i*4+3];
      #pragma unroll
      for (int nn=0;nn<2;nn++){
        float d00_ = D[nn][0] + REG, d11_ = D[nn][1] + REG;
        float2 d01 = make_float2(D[nn][2], D[nn][3]);
        float2 d10 = cconj(d01);
        float2 A00 = cadd(cscale(w00, d00_), cmul(w01, d10));
        float2 A01 = cadd(cmul(w00, d01), cscale(w01, d11_));
        float2 A10 = cadd(cscale(w10, d00_), cmul(w11, d10));
        float2 A11 = cadd(cmul(w10, d01), cscale(w11, d11_));
        float2 det = csub(cmul(A00,A11), cmul(A01,A10));
        float2 bu0, bu1;
        if (nn==0){ bu0 = A11; bu1 = make_float2(-A10.x, -A10.y); }
        else      { bu0 = make_float2(-A01.x, -A01.y); bu1 = A00; }
        float2 b0 = cdivc(bu0, det);
        float2 b1 = cdivc(bu1, det);
        float quad = d00_*(b0.x*b0.x + b0.y*b0.y) + d11_*(b1.x*b1.x + b1.y*b1.y);
        float2 u = cmul(d01, b1);
        quad += 2.0f*(b0.x*u.x + b0.y*u.y);
        float inv = 1.0f/sqrtf(quad + EPS);
        float2 wn0 = make_float2(b0.x*inv, -b0.y*inv);
        float2 wn1 = make_float2(b1.x*inv, -b1.y*inv);
        if (nn==0){ w00=wn0; w01=wn1; } else { w10=wn0; w11=wn1; }
      }
      Wm[i*4+0]=w00; Wm[i*4+1]=w01; Wm[i*4+2]=w10; Wm[i*4+3]=w11;
      wsh[0]=w00.x; wsh[1]=w00.y; wsh[2]=w01.x; wsh[3]=w01.y;
      wsh[4]=w10.x; wsh[5]=w10.y; wsh[6]=w11.x; wsh[7]=w11.y;
    }
  } else {
    if (tid < 4){ float2 w = Wm[i*4+tid]; wsh[tid*2]=w.x; wsh[tid*2+1]=w.y; }
  }
  __syncthreads();
  if (!(MODE & MODE_NMF)) return;

  // save T_old for k_vupd's p,q recompute
  if ((tid & 127) < 8){
    int kk = tid & 7;
    Told[(size_t)(n*K_DIM+kk)*I_DIM + i] = t[kk];
  }

  float2 w0 = make_float2(wsh[n*4+0], wsh[n*4+1]);
  float2 w1 = make_float2(wsh[n*4+2], wsh[n*4+3]);
  float aN[8] = {0,0,0,0,0,0,0,0};
  float aD[8] = {0,0,0,0,0,0,0,0};
  #pragma unroll
  for (int s=0;s<8;s++){
    float4 x = x_s[s];
    float yre = w0.x*x.x - w0.y*x.y + w1.x*x.z - w1.y*x.w;
    float yim = w0.x*x.y + w0.y*x.x + w1.x*x.w + w1.y*x.z;
    float q = q_s[s];
    float p = (yre*yre + yim*yim)*q*q;
    int j = jl + 128*s;
    float4 va = vb[j*2+0], vc = vb[j*2+1];
    aN[0]+=p*va.x; aN[1]+=p*va.y; aN[2]+=p*va.z; aN[3]+=p*va.w;
    aN[4]+=p*vc.x; aN[5]+=p*vc.y; aN[6]+=p*vc.z; aN[7]+=p*vc.w;
    aD[0]+=q*va.x; aD[1]+=q*va.y; aD[2]+=q*va.z; aD[3]+=q*va.w;
    aD[4]+=q*vc.x; aD[5]+=q*vc.y; aD[6]+=q*vc.z; aD[7]+=q*vc.w;
  }
  #pragma unroll
  for (int k=0;k<8;k++){
    #pragma unroll
    for (int off=32; off>0; off>>=1){
      aN[k] += __shfl_down(aN[k],off);
      aD[k] += __shfl_down(aD[k],off);
    }
  }
  {
    int lane = tid&63, wv = tid>>6;
    if (lane==0){
      #pragma unroll
      for (int k=0;k<8;k++){ redT[wv][k]=aN[k]; redT[wv][k+8]=aD[k]; }
    }
  }
  __syncthreads();
  if ((tid & 127) < 8){
    int kk = tid & 7;
    int wb = (tid>>7)*2;
    float ns = redT[wb][kk]   + redT[wb+1][kk];
    float ds = redT[wb][kk+8] + redT[wb+1][kk+8];
    size_t ti = (size_t)(n*K_DIM+kk)*I_DIM + i;
    Tw[ti] = Tw[ti]*sqrtf(ns*__frcp(ds + EPS));
  }
}

// ---- V-update: recompute p,q from (XcT, T_old, W), reduce over I, scale V ----
// grid (J/2, 2); block 256 = 128 i-lanes x 2 j. V in [n][j][k].
__global__ __launch_bounds__(256) void k_vupd(const float4* __restrict__ XcT,
      const float* __restrict__ Tw, const float* __restrict__ Told,
      float* __restrict__ Vw, const float2* __restrict__ Wm){
  int n = blockIdx.y;
  int tid = threadIdx.x;
  int jj = tid & 1, ii = tid >> 1;
  int j = blockIdx.x*2 + jj;
  const float4* vj = (const float4*)(Vw + ((size_t)n*J_DIM + j)*8);
  float4 va = vj[0], vc = vj[1];     // broadcast within jj-group
  float aN[8] = {0,0,0,0,0,0,0,0};
  float aD[8] = {0,0,0,0,0,0,0,0};
  const float* tob = Told + (size_t)(n*K_DIM)*I_DIM;
  const float* tnb = Tw   + (size_t)(n*K_DIM)*I_DIM;
  const float4* xcb = XcT + (size_t)j*I_DIM;
  #pragma unroll 2
  for (int i=ii; i<I_DIM; i+=128){
    float to[8], tn[8];
    #pragma unroll
    for (int k=0;k<8;k++){ to[k] = tob[k*I_DIM + i]; tn[k] = tnb[k*I_DIM + i]; }
    float4 wv = *(const float4*)&Wm[i*4 + n*2];
    float4 x  = xcb[i];                        // coalesced in i
    float r = to[0]*va.x+to[1]*va.y+to[2]*va.z+to[3]*va.w
            + to[4]*vc.x+to[5]*vc.y+to[6]*vc.z+to[7]*vc.w;
    float yre = wv.x*x.x - wv.y*x.y + wv.z*x.z - wv.w*x.w;
    float yim = wv.x*x.y + wv.y*x.x + wv.z*x.w + wv.w*x.z;
    float q = __frcp(r + EPS);
    float p = (yre*yre + yim*yim)*q*q;
    #pragma unroll
    for (int k=0;k<8;k++){ aN[k] += tn[k]*p; aD[k] += tn[k]*q; }
  }
  // reduce over ii within wave (lanes with same jj: even strides down to 2)
  #pragma unroll
  for (int k=0;k<8;k++){
    #pragma unroll
    for (int off=32; off>=2; off>>=1){
      aN[k] += __shfl_down(aN[k],off);
      aD[k] += __shfl_down(aD[k],off);
    }
  }
  __shared__ float red[4][2][16];   // [wave][jj][k | k+8]
  int wv_ = tid>>6, lane = tid&63;
  if (lane < 2){
    #pragma unroll
    for (int k=0;k<8;k++){ red[wv_][lane][k]=aN[k]; red[wv_][lane][k+8]=aD[k]; }
  }
  __syncthreads();
  if (tid < 16){
    int jj2 = tid>>3, k = tid&7;
    float num = red[0][jj2][k]+red[1][jj2][k]+red[2][jj2][k]+red[3][jj2][k];
    float den = red[0][jj2][k+8]+red[1][jj2][k+8]+red[2][jj2][k+8]+red[3][jj2][k+8];
    size_t vi = ((size_t)n*J_DIM + blockIdx.x*2 + jj2)*8 + k;
    Vw[vi] *= sqrtf(num*__frcp(den + EPS));
  }
}

// ---- final: Y = W @ X, write out [N,J,I,2] (transpose via LDS tile) ----
__global__ void k_final(const float4* __restrict__ Xc4, const float2* __restrict__ Wm,
                        float2* __restrict__ out){
  __shared__ float2 yt[2][32][33];
  int i0 = blockIdx.x*32, j0 = blockIdx.y*32;
  int tx = threadIdx.x, ty = threadIdx.y;
  int j = j0 + tx;
  #pragma unroll
  for (int r=0;r<4;r++){
    int il = ty + r*8; int i = i0 + il;
    if (i < I_DIM){
      float4 x = Xc4[(size_t)i*J_DIM + j];
      #pragma unroll
      for (int n=0;n<2;n++){
        float2 a = Wm[i*4+n*2+0], b = Wm[i*4+n*2+1];
        float2 y;
        y.x = a.x*x.x - a.y*x.y + b.x*x.z - b.y*x.w;
        y.y = a.x*x.y + a.y*x.x + b.x*x.w + b.y*x.z;
        yt[n][tx][il] = y;
      }
    }
  }
  __syncthreads();
  int i = i0 + tx;
  if (i < I_DIM){
    #pragma unroll
    for (int n=0;n<2;n++){
      #pragma unroll
      for (int r=0;r<4;r++){
        int jl = ty + r*8;
        out[(size_t)(n*J_DIM + j0 + jl)*I_DIM + i] = yt[n][jl][tx];
      }
    }
  }
}

extern "C" void kernel_launch(void* const* d_in, const int* in_sizes, int n_in,
                              void* d_out, int out_size, void* d_ws, size_t ws_size,
                              hipStream_t stream){
  const float2* X  = (const float2*)d_in[0];   // [M,J,I,2]
  const float*  T0 = (const float*)d_in[1];    // [I,K,M]
  const float*  V0 = (const float*)d_in[2];    // [K,J,M]

  char* ws = (char*)d_ws;
  size_t off = 0;
  auto alloc = [&](size_t bytes)->char*{
    char* p = ws + off; off += (bytes + 255) & ~(size_t)255; return p;
  };
  float4* Xc4  = (float4*)alloc((size_t)I_DIM*J_DIM*sizeof(float4));
  float4* XcT  = (float4*)alloc((size_t)J_DIM*I_DIM*sizeof(float4));
  float*  Tw   = (float*) alloc((size_t)2*K_DIM*I_DIM*sizeof(float));
  float*  Told = (float*) alloc((size_t)2*K_DIM*I_DIM*sizeof(float));
  float*  Vw   = (float*) alloc((size_t)2*J_DIM*K_DIM*sizeof(float));
  float2* Wm   = (float2*)alloc((size_t)I_DIM*4*sizeof(float2));

  k_setup<<<33*32, 256, 0, stream>>>(X, T0, V0, Xc4, XcT, Tw, Vw, Wm);
  // A0: NMF T-update of body 0 (W = identity), saves T_old
  k_cda<MODE_NMF><<<I_DIM, 256, 0, stream>>>(Xc4, Tw, Told, (const float4*)Vw, Wm);
  for (int it=0; it<N_ITER; it++){
    k_vupd<<<dim3(J_DIM/2, 2), 256, 0, stream>>>(XcT, Tw, Told, Vw, Wm);
    if (it < N_ITER-1)
      k_cda<MODE_CD|MODE_NMF><<<I_DIM, 256, 0, stream>>>(Xc4, Tw, Told, (const float4*)Vw, Wm);
    else
      k_cda<MODE_CD><<<I_DIM, 256, 0, stream>>>(Xc4, Tw, Told, (const float4*)Vw, Wm);
  }
  k_final<<<dim3(33,32), dim3(32,8), 0, stream>>>(Xc4, Wm, (float2*)d_out);
}